// Round 5
// baseline (34.345 us; speedup 1.0000x reference)
//
#include <hip/hip_runtime.h>
#include <hip/hip_bf16.h>

#define NB 16
#define NN 50
#define HW 256

// round(linspace(0,256,256))[i] == i + (i>=128); no round-half ties within f32 error.
// Grid value set is {0..127} U {129..256}  (128 is missing).
__device__ __forceinline__ float gridc(int i) { return (float)(i + (i >= 128 ? 1 : 0)); }

// Nearest grid value to continuous coordinate c (c in [5,230] for this problem).
__device__ __forceinline__ float nearest_grid(float c) {
  float r = rintf(c);
  if (r == 128.0f) r = (c < 128.0f) ? 127.0f : 129.0f;  // 128 not in grid; tie -> equal dist
  return r;
}

// Single fused kernel. One block = one (b, dest-channel k, 32-row tile): 6400 blocks x 256.
// 32 KB store granule per block -> fine-grained tail; prep is VALU-only (5% busy) so the
// x8 per-channel redundancy is free. Steady state: pure coalesced float4 store stream.
__global__ void k_fused(const float* __restrict__ boxes, const float* __restrict__ labels,
                        float* __restrict__ out) {
  int blk = blockIdx.x;
  int tile = blk & 7;        // 0..7 -> rows tile*32 .. tile*32+31
  int bk = blk >> 3;         // b*NN + k (dest channel)
  int b = bk / NN;
  int k = bk - b * NN;
  int n = (k < 25) ? 2 * k : 2 * (k - 25) + 1;  // channel-shuffle source

  const float4* boxes4 = reinterpret_cast<const float4*>(boxes);
  int t = threadIdx.x;

  // ---- Phase 1 (wave 0): per-batch normalization constants, analytic min/max ----
  // Separable gaussian, all factors > 0: mask extreme = f1 * (1-D ex extreme) * (1-D ey extreme).
  // Max at nearest grid point to center; min at farthest grid endpoint (0 or 256).
  __shared__ float sS, sMns;
  float mn = INFINITY, mx = -INFINITY;
  if (t < NN) {
    float4 bx = boxes4[b * NN + t];
    float xc = bx.x + floorf(bx.z * 0.5f);
    float yc = bx.y + floorf(bx.w * 0.5f);
    float gnx = nearest_grid(xc), gfx = (xc > 128.0f) ? 0.0f : 256.0f;
    float gny = nearest_grid(yc), gfy = (yc > 128.0f) ? 0.0f : 256.0f;
    float dnx = gnx - xc, dfx = gfx - xc, dny = gny - yc, dfy = gfy - yc;
    float exmx = expf(-0.5f * (dnx * dnx) / (0.25f * bx.z));
    float exmn = expf(-0.5f * (dfx * dfx) / (0.25f * bx.z));
    float eymx = expf(-0.5f * (dny * dny) / (0.25f * bx.w));
    float eymn = expf(-0.5f * (dfy * dfy) / (0.25f * bx.w));
    float det = 0.0625f * bx.z * bx.w;
    float f1 = 0.15915494309189535f / sqrtf(det);  // (2*pi)^-1 * det^-0.5
    mn = f1 * exmn * eymn;
    mx = f1 * exmx * eymx;
  }
  if (t < 64) {  // wave 0 reduces channels 0..49 (lanes 50..63 hold identities)
#pragma unroll
    for (int o = 32; o > 0; o >>= 1) {
      mn = fminf(mn, __shfl_xor(mn, o));
      mx = fmaxf(mx, __shfl_xor(mx, o));
    }
    if (t == 0) {
      float s = 50.0f / (mx - mn);  // SCALE_FACTOR / (mx - mn)
      sS = s;
      sMns = mn * s;
    }
  }

  // ---- labels: the 16 (k==0, tile==0) blocks write their batch's 50 permuted labels ----
  if (k == 0 && tile == 0 && t < NN) {
    int src = (t < 25) ? 2 * t : 2 * (t - 25) + 1;
    out[(size_t)NB * NN * HW * HW + b * NN + t] = labels[b * NN + src];
  }

  // ---- Phase 2: separable exp tables for THIS channel / tile ----
  float4 box = boxes4[b * NN + n];
  float xc = box.x + floorf(box.z * 0.5f);
  float yc = box.y + floorf(box.w * 0.5f);
  float det = 0.0625f * box.z * box.w;
  float f1 = 0.15915494309189535f / sqrtf(det);

  __shared__ float eyL[HW];
  __shared__ float exL[32];
  int row0 = tile * 32;
  {
    float g = gridc(t);
    float dy = g - yc;
    eyL[t] = expf(-0.5f * (dy * dy) / (0.25f * box.w));
  }
  if (t < 32) {
    float g = gridc(row0 + t);
    float dx = g - xc;
    exL[t] = expf(-0.5f * (dx * dx) / (0.25f * box.z));
  }
  __syncthreads();

  float A = f1 * sS;     // folded factor1 * scale
  float mns = sMns;

  int lane_col = (t & 63) * 4;  // one 64-lane wave spans a 1 KB row, float4 each
  int rsub = t >> 6;            // 0..3: 4 waves write 4 consecutive rows -> 4 KB bursts
  float eyr[4];
#pragma unroll
  for (int c = 0; c < 4; ++c) eyr[c] = A * eyL[lane_col + c];  // A folded, reused 8x

  float* base = out + (size_t)bk * (HW * HW) + (size_t)row0 * HW;
#pragma unroll
  for (int it = 0; it < 8; ++it) {
    int r = rsub + it * 4;      // 0..31 within tile
    float coef = exL[r];
    float4 v;
    v.x = fmaf(coef, eyr[0], -mns);   // mask*s - mn*s
    v.y = fmaf(coef, eyr[1], -mns);
    v.z = fmaf(coef, eyr[2], -mns);
    v.w = fmaf(coef, eyr[3], -mns);
    *reinterpret_cast<float4*>(base + r * HW + lane_col) = v;
  }
}

extern "C" void kernel_launch(void* const* d_in, const int* in_sizes, int n_in,
                              void* d_out, int out_size, void* d_ws, size_t ws_size,
                              hipStream_t stream) {
  const float* boxes = (const float*)d_in[0];
  const float* labels = (const float*)d_in[1];
  float* out = (float*)d_out;
  k_fused<<<NB * NN * 8, 256, 0, stream>>>(boxes, labels, out);
}

// Round 6
// 33.156 us; speedup vs baseline: 1.0359x; 1.0359x over previous
//
#include <hip/hip_runtime.h>
#include <hip/hip_bf16.h>

#define NB 16
#define NN 50
#define HW 256

// round(linspace(0,256,256))[i] == i + (i>=128); no round-half ties within f32 error.
// Grid value set is {0..127} U {129..256}  (128 is missing).
__device__ __forceinline__ float gridc(int i) { return (float)(i + (i >= 128 ? 1 : 0)); }

// Nearest grid value to continuous coordinate c (c in [5,230] for this problem).
__device__ __forceinline__ float nearest_grid(float c) {
  float r = rintf(c);
  if (r == 128.0f) r = (c < 128.0f) ? 127.0f : 129.0f;  // 128 not in grid; tie -> equal dist
  return r;
}

// Balanced persistent grid: 1280 blocks (exactly 5 per CU), each owns 5 consecutive
// 32-row tiles inside ONE batch (16 batches x 80 blocks x 5 tiles = 6400 tiles).
// Zero tail imbalance; batch min/max prep once per block; per-tile work = 256-expf
// LDS table rebuild + 8 coalesced float4 stores per thread (32 KB).
__global__ void k_fused(const float* __restrict__ boxes, const float* __restrict__ labels,
                        float* __restrict__ out) {
  int blk = blockIdx.x;
  int b = blk / 80;          // batch
  int slot = blk - b * 80;   // 0..79 within batch

  const float4* boxes4 = reinterpret_cast<const float4*>(boxes);
  int t = threadIdx.x;

  // ---- Phase 1 (wave 0): per-batch normalization constants, analytic min/max ----
  // Separable gaussian, all factors > 0: mask extreme = f1 * (1-D ex extreme) * (1-D ey extreme).
  // Max at nearest grid point to center; min at farthest grid endpoint (0 or 256).
  __shared__ float sS, sMns;
  float mn = INFINITY, mx = -INFINITY;
  if (t < NN) {
    float4 bx = boxes4[b * NN + t];
    float xc = bx.x + floorf(bx.z * 0.5f);
    float yc = bx.y + floorf(bx.w * 0.5f);
    float gnx = nearest_grid(xc), gfx = (xc > 128.0f) ? 0.0f : 256.0f;
    float gny = nearest_grid(yc), gfy = (yc > 128.0f) ? 0.0f : 256.0f;
    float dnx = gnx - xc, dfx = gfx - xc, dny = gny - yc, dfy = gfy - yc;
    float exmx = expf(-0.5f * (dnx * dnx) / (0.25f * bx.z));
    float exmn = expf(-0.5f * (dfx * dfx) / (0.25f * bx.z));
    float eymx = expf(-0.5f * (dny * dny) / (0.25f * bx.w));
    float eymn = expf(-0.5f * (dfy * dfy) / (0.25f * bx.w));
    float det = 0.0625f * bx.z * bx.w;
    float f1 = 0.15915494309189535f / sqrtf(det);  // (2*pi)^-1 * det^-0.5
    mn = f1 * exmn * eymn;
    mx = f1 * exmx * eymx;
  }
  if (t < 64) {  // wave 0 reduces channels 0..49 (lanes 50..63 hold identities)
#pragma unroll
    for (int o = 32; o > 0; o >>= 1) {
      mn = fminf(mn, __shfl_xor(mn, o));
      mx = fmaxf(mx, __shfl_xor(mx, o));
    }
    if (t == 0) {
      float s = 50.0f / (mx - mn);  // SCALE_FACTOR / (mx - mn)
      sS = s;
      sMns = mn * s;
    }
  }

  // ---- labels: one block per batch (slot==0) writes the 50 permuted labels ----
  if (slot == 0 && t < NN) {
    int src = (t < 25) ? 2 * t : 2 * (t - 25) + 1;
    out[(size_t)NB * NN * HW * HW + b * NN + t] = labels[b * NN + src];
  }

  __shared__ float eyL[HW];
  __shared__ float exL[32];

  int lane_col = (t & 63) * 4;  // one 64-lane wave spans a 1 KB row, float4 each
  int rsub = t >> 6;            // 0..3: 4 waves write 4 consecutive rows -> 4 KB bursts
  float g_t = gridc(t);
  float g_r = gridc(0);         // placeholder; recomputed per tile below

  // 5 consecutive tiles: tile_global = slot*5 + i  (0..399 within batch)
#pragma unroll
  for (int i = 0; i < 5; ++i) {
    int tg = slot * 5 + i;
    int k = tg >> 3;            // dest channel 0..49
    int tile = tg & 7;          // 0..7 -> rows tile*32..tile*32+31
    int n = (k < 25) ? 2 * k : 2 * (k - 25) + 1;  // channel-shuffle source

    float4 box = boxes4[b * NN + n];
    float xc = box.x + floorf(box.z * 0.5f);
    float yc = box.y + floorf(box.w * 0.5f);
    float det = 0.0625f * box.z * box.w;
    float f1 = 0.15915494309189535f / sqrtf(det);

    __syncthreads();  // WAR: previous tile's readers done before overwrite
    int row0 = tile * 32;
    {
      float dy = g_t - yc;
      eyL[t] = expf(-0.5f * (dy * dy) / (0.25f * box.w));
    }
    if (t < 32) {
      float g = gridc(row0 + t);
      float dx = g - xc;
      exL[t] = expf(-0.5f * (dx * dx) / (0.25f * box.z));
    }
    __syncthreads();  // RAW: tables ready

    float A = f1 * sS;
    float mns = sMns;
    float eyr[4];
#pragma unroll
    for (int c = 0; c < 4; ++c) eyr[c] = A * eyL[lane_col + c];

    float* base = out + ((size_t)b * NN + k) * (HW * HW) + (size_t)row0 * HW;
#pragma unroll
    for (int it = 0; it < 8; ++it) {
      int r = rsub + it * 4;      // 0..31 within tile
      float coef = exL[r];
      float4 v;
      v.x = fmaf(coef, eyr[0], -mns);   // mask*s - mn*s
      v.y = fmaf(coef, eyr[1], -mns);
      v.z = fmaf(coef, eyr[2], -mns);
      v.w = fmaf(coef, eyr[3], -mns);
      *reinterpret_cast<float4*>(base + r * HW + lane_col) = v;
    }
  }
  (void)g_r;
}

extern "C" void kernel_launch(void* const* d_in, const int* in_sizes, int n_in,
                              void* d_out, int out_size, void* d_ws, size_t ws_size,
                              hipStream_t stream) {
  const float* boxes = (const float*)d_in[0];
  const float* labels = (const float*)d_in[1];
  float* out = (float*)d_out;
  k_fused<<<1280, 256, 0, stream>>>(boxes, labels, out);
}